// Round 1
// 256.202 us; speedup vs baseline: 1.0310x; 1.0310x over previous
//
#include <hip/hip_runtime.h>
#include <hip/hip_bf16.h>

typedef unsigned short ushort_t;
typedef __attribute__((ext_vector_type(8))) short short8;
typedef __attribute__((ext_vector_type(4))) float floatx4;

#define LOG2E 1.4426950408889634f

__device__ __forceinline__ unsigned short f2bf(float f) {
    unsigned u = __float_as_uint(f);
    u += 0x7FFF + ((u >> 16) & 1);   // RNE
    return (unsigned short)(u >> 16);
}

__device__ __forceinline__ void async_ld16(const void* gptr, void* lptr) {
    typedef const __attribute__((address_space(1))) unsigned int TG;
    typedef __attribute__((address_space(3))) unsigned int TL;
    __builtin_amdgcn_global_load_lds((TG*)(unsigned long long)gptr,
                                     (TL*)(unsigned)(unsigned long long)lptr,
                                     16, 0, 0);
}

// ---------------- fused prep: x->bf16 | w_qkv transpose | w_proj transpose ----------------
__global__ __launch_bounds__(256) void prep_kernel(const float* __restrict__ x,
                                                   const float* __restrict__ wqkv,
                                                   const float* __restrict__ wproj,
                                                   ushort_t* __restrict__ xb,
                                                   ushort_t* __restrict__ wqkvT,
                                                   ushort_t* __restrict__ wprojT) {
    __shared__ float t[32][33];
    int bx = blockIdx.x;
    if (bx < 8192) {
        int i = bx * 256 + threadIdx.x;
        float4 v = ((const float4*)x)[i];
        unsigned long long r = (unsigned long long)f2bf(v.x)
                             | ((unsigned long long)f2bf(v.y) << 16)
                             | ((unsigned long long)f2bf(v.z) << 32)
                             | ((unsigned long long)f2bf(v.w) << 48);
        ((unsigned long long*)xb)[i] = r;
        return;
    }
    const float* in; ushort_t* out; int R, C, bidx;
    if (bx < 8192 + 3072) { in = wqkv; out = wqkvT; R = 1024; C = 3072; bidx = bx - 8192; }
    else                  { in = wproj; out = wprojT; R = 1024; C = 1024; bidx = bx - 11264; }
    int nbc = C >> 5;
    int bc = bidx % nbc, br = bidx / nbc;
    int tx = threadIdx.x & 31, ty = threadIdx.x >> 5;   // 32 x 8
    int r0 = br << 5, c0 = bc << 5;
#pragma unroll
    for (int j = 0; j < 4; ++j)
        t[ty + j * 8][tx] = in[(size_t)(r0 + ty + j * 8) * C + c0 + tx];
    __syncthreads();
#pragma unroll
    for (int j = 0; j < 4; ++j)
        out[(size_t)(c0 + ty + j * 8) * R + r0 + tx] = f2bf(t[tx][ty + j * 8]);
}

// ---------------- QKV GEMM: 256x256 tile, BK=64, 8-phase pipelined schedule ----------------
// T1 XCD swizzle + T2 XOR-swizzled LDS + T3/T4 counted-vmcnt 8-phase + T5 setprio.
// A [8192,1024] bf16, Bt [3072,1024] bf16 (=W^T); C -> Q/K [bh][s][64], Vt [bh][64][2048];
// Q (incl bias) pre-scaled by 0.125*log2(e).
// 512 thr = 8 waves (2M x 4N), wave owns 128x64. LDS: 2 dbuf x (A 2x[128][64] + B 2x[128][64])
// = 128 KB; epilogue restage reuses up to 144 KB (dynamic LDS, 1 block/CU by design).
// Per K-tile X, quadrant order Q00,Q01,Q11,Q10:
//   ph0: ds A[qm0](8)+B[qn0](4); stage A1(X+1) | ph1: ds B[qn1](4); stage B0(X+2)
//   ph2: ds A[qm1](8);           stage B1(X+2) | ph3: stage A0(X+2); vmcnt(6)
// each phase: [reads|stage] -> s_barrier -> lgkmcnt(0) -> setprio(1) -> 16 MFMA -> setprio(0)
// -> s_barrier. vmcnt(6) (=3 half-tiles in flight) guards tile X+1; never 0 until tail.
// Staging legality: a region is overwritten only after the phase-end barrier of its last read
// (B0 read ph0, B1 read ph1, A halves read ph0+ph2). Swizzle: linear LDS dest, source chunk
// pre-swizzled (chunk ^= row&7), same XOR on ds_read -> ~2-way residual conflicts.
__global__ __launch_bounds__(512) void gemm_qkv_kernel(const ushort_t* __restrict__ A,
                                                       const ushort_t* __restrict__ Bt,
                                                       const float* __restrict__ bias,
                                                       ushort_t* __restrict__ qbuf,
                                                       ushort_t* __restrict__ kbuf,
                                                       ushort_t* __restrict__ vtbuf) {
    extern __shared__ __align__(16) ushort_t lds[];

    int bid = blockIdx.x;
    int wg = (bid & 7) * 48 + (bid >> 3);      // XCD-bijective swizzle (384 % 8 == 0)
    int bm = wg & 31, bn = wg >> 5;            // 32 x 12
    int m0 = bm << 8, n0 = bn << 8;

    int tid = threadIdx.x;
    int wave = tid >> 6, lane = tid & 63;
    int c = lane & 15, g = lane >> 4;
    int wm = wave >> 2, wn = wave & 3;

    // staging: thread handles rows (tid>>3) and (tid>>3)+64 of a [128][64] half,
    // chunk (tid&7), source chunk XOR'd by row&7 (read side applies same XOR).
    int row0 = tid >> 3;
    int sch  = (tid & 7) ^ (row0 & 7);
    size_t aoff = (size_t)(m0 + row0) * 1024 + sch * 8;
    size_t boff = (size_t)(n0 + row0) * 1024 + sch * 8;

    // per-lane swizzled k-chunk offsets for ds_read_b128 (ushort units)
    int co0 = (g * 8) ^ ((c & 7) << 3);
    int co1 = co0 ^ 32;
    int Ab0 = wm * 8192,                 Ab1 = Ab0 + 16384;
    int Bb0 = 32768 + (wn >> 1) * 8192,  Bb1 = Bb0 + 16384;
    int bcol = (wn & 1) * 64;

    floatx4 acc[8][4];
    short8 a[4][2], b0f[2][2], b1f[2][2];
#pragma unroll
    for (int i2 = 0; i2 < 8; ++i2)
#pragma unroll
        for (int j2 = 0; j2 < 4; ++j2) { floatx4 z = {0.f,0.f,0.f,0.f}; acc[i2][j2] = z; }

    auto stA = [&](int t, int h, int buf) {
        const ushort_t* s = A + aoff + (size_t)h * 131072 + (size_t)t * 64;
        ushort_t* d = lds + buf * 16384 + h * 8192 + tid * 8;
        async_ld16(s, d);
        async_ld16(s + 65536, d + 4096);
    };
    auto stB = [&](int t, int h, int buf) {
        const ushort_t* s = Bt + boff + (size_t)h * 131072 + (size_t)t * 64;
        ushort_t* d = lds + 32768 + buf * 16384 + h * 8192 + tid * 8;
        async_ld16(s, d);
        async_ld16(s + 65536, d + 4096);
    };
    auto ld_a = [&](int abase, int qm) {
#pragma unroll
        for (int mi = 0; mi < 4; ++mi) {
            int ro = abase + (qm * 64 + mi * 16 + c) * 64;
            a[mi][0] = *(const short8*)&lds[ro + co0];
            a[mi][1] = *(const short8*)&lds[ro + co1];
        }
    };
    auto ld_b = [&](int bbase, int qn, short8 (&bf)[2][2]) {
#pragma unroll
        for (int nii = 0; nii < 2; ++nii) {
            int ro = bbase + (bcol + (qn * 2 + nii) * 16 + c) * 64;
            bf[nii][0] = *(const short8*)&lds[ro + co0];
            bf[nii][1] = *(const short8*)&lds[ro + co1];
        }
    };
    auto phase_mm = [&](int qm, int qn, short8 (&bf)[2][2]) {
        asm volatile("s_barrier" ::: "memory");
        asm volatile("s_waitcnt lgkmcnt(0)" ::: "memory");
        __builtin_amdgcn_s_setprio(1);
#pragma unroll
        for (int mi = 0; mi < 4; ++mi)
#pragma unroll
            for (int nii = 0; nii < 2; ++nii)
#pragma unroll
                for (int ks = 0; ks < 2; ++ks)
                    acc[qm * 4 + mi][qn * 2 + nii] =
                        __builtin_amdgcn_mfma_f32_16x16x32_bf16(
                            a[mi][ks], bf[nii][ks], acc[qm * 4 + mi][qn * 2 + nii], 0, 0, 0);
        __builtin_amdgcn_s_setprio(0);
        asm volatile("s_barrier" ::: "memory");
    };

    // prologue: tile0 fully + 3 half-tiles of tile1; wait tile0, keep 3 HT in flight
    stA(0, 0, 0); stA(0, 1, 0); stB(0, 0, 0); stB(0, 1, 0);
    stA(1, 0, 1); stB(1, 0, 1); stB(1, 1, 1);
    asm volatile("s_waitcnt vmcnt(6)" ::: "memory");
    asm volatile("s_barrier" ::: "memory");

#pragma unroll 1
    for (int i = 0; i < 7; ++i) {
        int t0 = 2 * i;
        // ---- tile t0 (buf0) ----
        ld_a(Ab0, 0); ld_b(Bb0, 0, b0f);
        stA(t0 + 1, 1, 1);
        phase_mm(0, 0, b0f);
        ld_b(Bb0, 1, b1f);
        stB(t0 + 2, 0, 0);
        phase_mm(0, 1, b1f);
        ld_a(Ab0, 1);
        stB(t0 + 2, 1, 0);
        phase_mm(1, 1, b1f);
        stA(t0 + 2, 0, 0);
        asm volatile("s_waitcnt vmcnt(6)" ::: "memory");
        phase_mm(1, 0, b0f);
        // ---- tile t0+1 (buf1) ----
        ld_a(Ab1, 0); ld_b(Bb1, 0, b0f);
        stA(t0 + 2, 1, 0);
        phase_mm(0, 0, b0f);
        ld_b(Bb1, 1, b1f);
        stB(t0 + 3, 0, 1);
        phase_mm(0, 1, b1f);
        ld_a(Ab1, 1);
        stB(t0 + 3, 1, 1);
        phase_mm(1, 1, b1f);
        stA(t0 + 3, 0, 1);
        asm volatile("s_waitcnt vmcnt(6)" ::: "memory");
        phase_mm(1, 0, b0f);
    }
    // ---- tail: tile 14 (buf0) ----
    ld_a(Ab0, 0); ld_b(Bb0, 0, b0f);
    stA(15, 1, 1);
    phase_mm(0, 0, b0f);
    ld_b(Bb0, 1, b1f);
    phase_mm(0, 1, b1f);
    ld_a(Ab0, 1);
    phase_mm(1, 1, b1f);
    asm volatile("s_waitcnt vmcnt(0)" ::: "memory");
    phase_mm(1, 0, b0f);
    // ---- tile 15 (buf1) ----
    ld_a(Ab1, 0); ld_b(Bb1, 0, b0f);
    phase_mm(0, 0, b0f);
    ld_b(Bb1, 1, b1f);
    phase_mm(0, 1, b1f);
    ld_a(Ab1, 1);
    phase_mm(1, 1, b1f);
    phase_mm(1, 0, b0f);

    // ---------------- epilogue: restage C-tile through LDS, split Q/K/Vt ----------------
    int sec = n0 >> 10;               // 0=Q 1=K 2=V (tile never crosses a 1024 boundary)
    int h0 = (n0 & 1023) >> 6;        // first head of this 256-col tile (4 heads, head=wn)
    int b  = m0 >> 11, sbase = m0 & 2047;
    int bh0 = b * 16 + h0;
    float bv[4];
#pragma unroll
    for (int ni = 0; ni < 4; ++ni) bv[ni] = bias[n0 + wn * 64 + ni * 16 + c];

    __syncthreads();                  // loop fully drained; reuse LDS for staging

    if (sec < 2) {
        // stage [head][row 256][col 64], row stride 72 (16B-aligned rows): 144 KB
        float scl = (sec == 0) ? (0.125f * LOG2E) : 1.0f;
#pragma unroll
        for (int mi8 = 0; mi8 < 8; ++mi8) {
            int sr0 = wm * 128 + (mi8 >> 2) * 64 + (mi8 & 3) * 16 + g * 4;
#pragma unroll
            for (int ni = 0; ni < 4; ++ni)
#pragma unroll
                for (int r = 0; r < 4; ++r)
                    lds[wn * 18432 + (sr0 + r) * 72 + ni * 16 + c] =
                        f2bf((acc[mi8][ni][r] + bv[ni]) * scl);
        }
        __syncthreads();
        // copy: wave -> 16 KB contiguous global region (head, 128-row half)
        ushort_t* dst = (sec == 0 ? qbuf : kbuf)
                      + (size_t)(bh0 + (wave & 3)) * 131072
                      + (size_t)(sbase + (wave >> 2) * 128) * 64;
        const ushort_t* srcb = lds + (wave & 3) * 18432 + (wave >> 2) * 128 * 72;
#pragma unroll
        for (int j = 0; j < 16; ++j) {
            int e = j * 512 + lane * 8;
            *(short8*)(dst + e) =
                *(const short8*)(srcb + (e >> 6) * 72 + (lane & 7) * 8);
        }
    } else {
        // stage [head][d 64][s 256], d stride 264; packed u64 along s: 132 KB
#pragma unroll
        for (int mi8 = 0; mi8 < 8; ++mi8) {
            int s0 = wm * 128 + (mi8 >> 2) * 64 + (mi8 & 3) * 16 + g * 4;
#pragma unroll
            for (int ni = 0; ni < 4; ++ni) {
                int d = ni * 16 + c;
                unsigned long long pk =
                      (unsigned long long)f2bf(acc[mi8][ni][0] + bv[ni])
                    | ((unsigned long long)f2bf(acc[mi8][ni][1] + bv[ni]) << 16)
                    | ((unsigned long long)f2bf(acc[mi8][ni][2] + bv[ni]) << 32)
                    | ((unsigned long long)f2bf(acc[mi8][ni][3] + bv[ni]) << 48);
                *(unsigned long long*)&lds[wn * 16896 + d * 264 + s0] = pk;
            }
        }
        __syncthreads();
        // copy: wave -> (head, 32-d block); 512B contiguous runs per d-row
        const ushort_t* srcb = lds + (wave & 3) * 16896 + (wave >> 2) * 32 * 264;
        ushort_t* dstb = vtbuf + (size_t)(bh0 + (wave & 3)) * 131072
                       + (size_t)((wave >> 2) * 32) * 2048 + sbase;
#pragma unroll
        for (int j = 0; j < 16; ++j) {
            int e = j * 512 + lane * 8;
            int d = e >> 8, sc = e & 255;
            *(short8*)(dstb + (size_t)d * 2048 + sc) =
                *(const short8*)(srcb + d * 264 + sc);
        }
    }
}

// ---------------- flash attention: 1 block = (b,h) x 64 q-rows, 64-kp tiles ----------------
// Single strip per wave; 26.1 KB LDS; (256,5) -> 5 blocks/CU spill-free.
// Conflict-free stride-68 LDS, transposed softmax, no online max, LPT
// dispatch, post-barrier register prefetch.
__global__ __launch_bounds__(256, 5) void attn_kernel(const ushort_t* __restrict__ qb_,
                                                      const ushort_t* __restrict__ kb_,
                                                      const ushort_t* __restrict__ vtb_,
                                                      ushort_t* __restrict__ aout) {
    __shared__ __align__(16) ushort_t Ks[64 * 68];       // [kp][d] stride 68
    __shared__ __align__(16) ushort_t Vs[64 * 68];       // [d][kp] stride 68
    __shared__ __align__(16) ushort_t Ps[4][16 * 68];    // per-wave P[q][kp]
    int bx = blockIdx.x;
    int qb = 31 - (bx >> 6);          // LPT: longest blocks dispatch first
    int bhix = bx & 63;
    int b = bhix >> 4, h = bhix & 15;
    int q0 = qb << 6;
    int tid = threadIdx.x, wave = tid >> 6, lane = tid & 63;
    int c = lane & 15, g = lane >> 4;
    size_t bh = (size_t)(b * 16 + h);

    const ushort_t* Qp = qb_ + (bh * 2048 + q0) * 64;
    const ushort_t* Kp = kb_ + bh * 131072;
    const ushort_t* Vp = vtb_ + bh * 131072;

    int qr = wave * 16 + c;
    short8 qf0 = *(const short8*)(Qp + qr * 64 + g * 8);
    short8 qf1 = *(const short8*)(Qp + qr * 64 + 32 + g * 8);

    float l_part = 0.f;
    floatx4 o_acc[4];
#pragma unroll
    for (int nt = 0; nt < 4; ++nt) { floatx4 z = {0.f,0.f,0.f,0.f}; o_acc[nt] = z; }

    short8 kreg[2], vreg[2];
#pragma unroll
    for (int it = 0; it < 2; ++it) {
        int idx = it * 256 + tid;
        kreg[it] = *(const short8*)(Kp + idx * 8);
        vreg[it] = *(const short8*)(Vp + (idx >> 3) * 2048 + (idx & 7) * 8);
    }

    int qg = q0 + wave * 16 + c;
    for (int kt = 0; kt <= qb; ++kt) {
        int kt0 = kt << 6;
        __syncthreads();
#pragma unroll
        for (int it = 0; it < 2; ++it) {
            int idx = it * 256 + tid;
            *(short8*)&Ks[(idx >> 3) * 68 + (idx & 7) * 8] = kreg[it];
            *(short8*)&Vs[(idx >> 3) * 68 + (idx & 7) * 8] = vreg[it];
        }
        __syncthreads();
        if (kt < qb) {
            int s0 = (kt + 1) << 6;
#pragma unroll
            for (int it = 0; it < 2; ++it) {
                int idx = it * 256 + tid;
                kreg[it] = *(const short8*)(Kp + s0 * 64 + idx * 8);
                vreg[it] = *(const short8*)(Vp + (idx >> 3) * 2048 + s0 + (idx & 7) * 8);
            }
        }
        bool diag = (kt == qb);

        float lp = 0.f;
#pragma unroll
        for (int nt = 0; nt < 4; ++nt) {
            short8 kf0 = *(const short8*)&Ks[(nt * 16 + c) * 68 + g * 8];
            short8 kf1 = *(const short8*)&Ks[(nt * 16 + c) * 68 + 32 + g * 8];
            floatx4 z = {0.f, 0.f, 0.f, 0.f};
            z = __builtin_amdgcn_mfma_f32_16x16x32_bf16(kf0, qf0, z, 0, 0, 0);
            z = __builtin_amdgcn_mfma_f32_16x16x32_bf16(kf1, qf1, z, 0, 0, 0);

            int kpb = kt0 + nt * 16 + g * 4;
            float p[4];
#pragma unroll
            for (int r = 0; r < 4; ++r) {
                float s = z[r];
                if (diag) s = (kpb + r > qg) ? -1e30f : s;
                p[r] = exp2f(s);
                lp += p[r];
            }
            union { unsigned long long u; __hip_bfloat162 h2[2]; } pk;
            pk.h2[0] = __float22bfloat162_rn(make_float2(p[0], p[1]));
            pk.h2[1] = __float22bfloat162_rn(make_float2(p[2], p[3]));
            *(unsigned long long*)&Ps[wave][c * 68 + nt * 16 + g * 4] = pk.u;
        }
        l_part += lp;

#pragma unroll
        for (int ks = 0; ks < 2; ++ks) {
            short8 pf = *(const short8*)&Ps[wave][c * 68 + ks * 32 + g * 8];
#pragma unroll
            for (int nt = 0; nt < 4; ++nt) {
                short8 vf = *(const short8*)&Vs[(nt * 16 + c) * 68 + ks * 32 + g * 8];
                o_acc[nt] = __builtin_amdgcn_mfma_f32_16x16x32_bf16(pf, vf, o_acc[nt], 0, 0, 0);
            }
        }
    }

    float l = l_part;
    l += __shfl_xor(l, 16);
    l += __shfl_xor(l, 32);
    float linv = 1.0f / l;
    float inv[4];
#pragma unroll
    for (int r = 0; r < 4; ++r)
        inv[r] = __shfl(linv, g * 4 + r);
#pragma unroll
    for (int nt = 0; nt < 4; ++nt)
#pragma unroll
        for (int r = 0; r < 4; ++r) {
            int q = q0 + wave * 16 + g * 4 + r;
            aout[(size_t)(b * 2048 + q) * 1024 + h * 64 + nt * 16 + c] =
                f2bf(o_acc[nt][r] * inv[r]);
        }
}

// ---------------- proj GEMM: [8192,1024]@[1024,1024]^T + bias -> fp32 ----------------
__global__ __launch_bounds__(256) void gemm_proj_kernel(const ushort_t* __restrict__ A,
                                                        const ushort_t* __restrict__ Bt,
                                                        const float* __restrict__ bias,
                                                        float* __restrict__ Cout) {
    const int K = 1024, N = 1024, nbn = 8;
    __shared__ __align__(16) ushort_t As[128 * 32];
    __shared__ __align__(16) ushort_t Bs[128 * 32];
    int bm = blockIdx.x / nbn, bn = blockIdx.x % nbn;
    int m0 = bm << 7, n0 = bn << 7;
    int tid = threadIdx.x;
    int wave = tid >> 6, lane = tid & 63;
    int c = lane & 15, g = lane >> 4;
    int m_off = (wave & 1) << 6, n_off = (wave >> 1) << 6;
    int ldrow = lane >> 2;
    int ldk   = (lane & 3) << 3;

    floatx4 acc[4][4];
#pragma unroll
    for (int mi = 0; mi < 4; ++mi)
#pragma unroll
        for (int ni = 0; ni < 4; ++ni) {
            floatx4 z = {0.f, 0.f, 0.f, 0.f};
            acc[mi][ni] = z;
        }

    for (int kk = 0; kk < K; kk += 32) {
        __syncthreads();
#pragma unroll
        for (int j = 0; j < 2; ++j) {
            int chunk = wave * 2 + j;
            async_ld16(A  + (size_t)(m0 + chunk * 16 + ldrow) * K + kk + ldk, &As[chunk * 512]);
            async_ld16(Bt + (size_t)(n0 + chunk * 16 + ldrow) * K + kk + ldk, &Bs[chunk * 512]);
        }
        __syncthreads();
        short8 bf[4];
#pragma unroll
        for (int ni = 0; ni < 4; ++ni)
            bf[ni] = *(const short8*)&Bs[(n_off + ni * 16 + c) * 32 + g * 8];
#pragma unroll
        for (int mi = 0; mi < 4; ++mi) {
            short8 af = *(const short8*)&As[(m_off + mi * 16 + c) * 32 + g * 8];
#pragma unroll
            for (int ni = 0; ni < 4; ++ni)
                acc[mi][ni] = __builtin_amdgcn_mfma_f32_16x16x32_bf16(af, bf[ni], acc[mi][ni], 0, 0, 0);
        }
    }

    float bv[4];
#pragma unroll
    for (int ni = 0; ni < 4; ++ni) bv[ni] = bias[n0 + n_off + ni * 16 + c];
#pragma unroll
    for (int mi = 0; mi < 4; ++mi)
#pragma unroll
        for (int ni = 0; ni < 4; ++ni)
#pragma unroll
            for (int r = 0; r < 4; ++r) {
                int row = m0 + m_off + mi * 16 + g * 4 + r;
                int col = n0 + n_off + ni * 16 + c;
                Cout[(size_t)row * N + col] = acc[mi][ni][r] + bv[ni];
            }
}

extern "C" void kernel_launch(void* const* d_in, const int* in_sizes, int n_in,
                              void* d_out, int out_size, void* d_ws, size_t ws_size,
                              hipStream_t stream) {
    const float* x        = (const float*)d_in[0];
    const float* c_attn_w = (const float*)d_in[1];
    const float* c_attn_b = (const float*)d_in[2];
    const float* c_proj_w = (const float*)d_in[3];
    const float* c_proj_b = (const float*)d_in[4];
    float* out = (float*)d_out;

    char* ws = (char*)d_ws;
    ushort_t* xb     = (ushort_t*)(ws);              // 16 MB; reused as attn output 'a'
    ushort_t* wqkvT  = (ushort_t*)(ws + 16777216);   // 6 MB
    ushort_t* wprojT = (ushort_t*)(ws + 23068672);   // 2 MB
    ushort_t* qbuf   = (ushort_t*)(ws + 25165824);   // 16 MB  [bh][s][64]  (pre-scaled)
    ushort_t* kbuf   = (ushort_t*)(ws + 41943040);   // 16 MB  [bh][s][64]
    ushort_t* vtbuf  = (ushort_t*)(ws + 58720256);   // 16 MB  [bh][64][2048]

    static bool s_attr_set = false;
    if (!s_attr_set) {
        (void)hipFuncSetAttribute(reinterpret_cast<const void*>(gemm_qkv_kernel),
                                  hipFuncAttributeMaxDynamicSharedMemorySize, 147456);
        s_attr_set = true;
    }

    prep_kernel<<<12288, 256, 0, stream>>>(x, c_attn_w, c_proj_w, xb, wqkvT, wprojT);
    gemm_qkv_kernel<<<384, 512, 147456, stream>>>(xb, wqkvT, c_attn_b, qbuf, kbuf, vtbuf);
    attn_kernel<<<2048, 256, 0, stream>>>(qbuf, kbuf, vtbuf, xb);
    gemm_proj_kernel<<<64 * 8, 256, 0, stream>>>(xb, wprojT, c_proj_b, out);
}